// Round 1
// baseline (302.276 us; speedup 1.0000x reference)
//
#include <hip/hip_runtime.h>

// LargeEmbedding: out[i, :] = pages_flat[indices[i], :]
// pages: [8, 125000, 64] f32 stacked contiguously -> flat [1e6, 64] table,
// since page_id*125000 + row_id == idx. Pure row gather, memory-bound.
//
// Layout: one float4 per thread; 16 lanes = one 256 B row, so each wave64
// issues 4 coalesced 256 B read segments + 1 KiB coalesced write.

__global__ __launch_bounds__(256) void LargeEmbedding_90494960927132_kernel(
    const int* __restrict__ indices,
    const float4* __restrict__ pages4,   // flat [1e6 * 16] float4
    float4* __restrict__ out4,
    int n4)                              // total float4 elements in output
{
    int g = blockIdx.x * 256 + threadIdx.x;
    if (g >= n4) return;
    int row = g >> 4;        // which output row (0 .. 131071)
    int sub = g & 15;        // which float4 within the 64-float row
    int idx = indices[row];  // 0 .. 999999; broadcast across 16 lanes -> L1 hit
    out4[g] = pages4[idx * 16 + sub];   // max 16e6, fits int32
}

extern "C" void kernel_launch(void* const* d_in, const int* in_sizes, int n_in,
                              void* d_out, int out_size, void* d_ws, size_t ws_size,
                              hipStream_t stream) {
    const int* indices   = (const int*)d_in[0];      // [16*8192] int32
    const float4* pages4 = (const float4*)d_in[1];   // [8*125000*64] f32 as float4
    float4* out4         = (float4*)d_out;

    int n4 = out_size / 4;               // 8,388,608 floats -> 2,097,152 float4
    int blocks = (n4 + 255) / 256;       // 8192 blocks
    LargeEmbedding_90494960927132_kernel<<<blocks, 256, 0, stream>>>(
        indices, pages4, out4, n4);
}

// Round 3
// 296.681 us; speedup vs baseline: 1.0189x; 1.0189x over previous
//
#include <hip/hip_runtime.h>

// LargeEmbedding: out[i, :] = pages_flat[indices[i], :]
// pages: [8, 125000, 64] f32 stacked contiguously; page_id*125000+row_id == idx,
// so this is a flat row gather of 256 B rows. Pure memory-bound.
//
// R3 = R2 with clang-native vector type (HIP float4 is a struct; the
// nontemporal builtins require a true vector type):
//  - 2 independent 16 B loads per thread -> better latency hiding.
//  - nontemporal loads (gathered rows are ~single-use) + nontemporal stores
//    (streaming output) -> less L2/L3 churn.

typedef float f32x4 __attribute__((ext_vector_type(4)));

__global__ __launch_bounds__(256) void LargeEmbedding_90494960927132_kernel(
    const int* __restrict__ indices,
    const f32x4* __restrict__ pages4,    // flat [1e6 * 16] x 16B
    f32x4* __restrict__ out4,
    int n4)                              // total 16B elements in output
{
    const int nthreads = gridDim.x * 256;          // n4 / 2
    int g0 = blockIdx.x * 256 + threadIdx.x;       // first float4
    int g1 = g0 + nthreads;                        // second float4 (independent)

    int row0 = g0 >> 4;
    int sub0 = g0 & 15;
    int idx0 = indices[row0];                      // 16-lane broadcast, L1 hit
    int row1 = g1 >> 4;
    int sub1 = g1 & 15;
    int idx1 = indices[row1];

    f32x4 v0 = __builtin_nontemporal_load(&pages4[idx0 * 16 + sub0]);
    f32x4 v1 = __builtin_nontemporal_load(&pages4[idx1 * 16 + sub1]);
    __builtin_nontemporal_store(v0, &out4[g0]);
    __builtin_nontemporal_store(v1, &out4[g1]);
}

extern "C" void kernel_launch(void* const* d_in, const int* in_sizes, int n_in,
                              void* d_out, int out_size, void* d_ws, size_t ws_size,
                              hipStream_t stream) {
    const int* indices  = (const int*)d_in[0];      // [16*8192] int32
    const f32x4* pages4 = (const f32x4*)d_in[1];    // [8*125000*64] f32 as 16B vecs
    f32x4* out4         = (f32x4*)d_out;

    int n4 = out_size / 4;               // 2,097,152 float4
    int blocks = n4 / (256 * 2);         // 4096 blocks, 2 float4/thread, exact
    LargeEmbedding_90494960927132_kernel<<<blocks, 256, 0, stream>>>(
        indices, pages4, out4, n4);
}